// Round 1
// baseline (1723.933 us; speedup 1.0000x reference)
//
#include <hip/hip_runtime.h>
#include <math.h>

// Problem constants
#define BATCH  4
#define LSEQ   2048
#define DMODEL 1024
#define MROWS  (BATCH * LSEQ)   // 8192
#define SCORE_SCALE 8.0f        // sqrt(1024/16), reference MULTIPLIES

// JAX threefry variant: 1 = partitionable (default in JAX >= 0.4.30):
//   bits[n] = o0^o1 of threefry2x32((0,42), (0, n))
// 0 = legacy split-iota scheme.
#define THREEFRY_PARTITIONABLE 1

__device__ __forceinline__ unsigned rotl32(unsigned x, int r) {
    return (x << r) | (x >> (32 - r));
}

__device__ __forceinline__ void threefry2x32(unsigned k0, unsigned k1,
                                             unsigned x0, unsigned x1,
                                             unsigned& o0, unsigned& o1) {
    const unsigned ks0 = k0, ks1 = k1, ks2 = k0 ^ k1 ^ 0x1BD11BDAu;
    x0 += ks0; x1 += ks1;
#define TF_R(r) { x0 += x1; x1 = rotl32(x1, r); x1 ^= x0; }
    TF_R(13) TF_R(15) TF_R(26) TF_R(6)
    x0 += ks1; x1 += ks2 + 1u;
    TF_R(17) TF_R(29) TF_R(16) TF_R(24)
    x0 += ks2; x1 += ks0 + 2u;
    TF_R(13) TF_R(15) TF_R(26) TF_R(6)
    x0 += ks0; x1 += ks1 + 3u;
    TF_R(17) TF_R(29) TF_R(16) TF_R(24)
    x0 += ks1; x1 += ks2 + 4u;
    TF_R(13) TF_R(15) TF_R(26) TF_R(6)
    x0 += ks2; x1 += ks0 + 5u;
#undef TF_R
    o0 = x0; o1 = x1;
}

// keep = (uniform < 0.5) <=> bits < 2^31  (exact: u = (bits>>9)*2^-23)
__device__ __forceinline__ bool dropout_keep(unsigned n) {
    unsigned o0, o1;
#if THREEFRY_PARTITIONABLE
    threefry2x32(0u, 42u, 0u, n, o0, o1);
    unsigned bits = o0 ^ o1;
#else
    const unsigned HALF = (unsigned)(BATCH * LSEQ) * (unsigned)LSEQ / 2u; // 8388608
    unsigned c0 = (n < HALF) ? n : (n - HALF);
    unsigned c1 = (n < HALF) ? (n + HALF) : n;
    threefry2x32(0u, 42u, c0, c1, o0, o1);
    unsigned bits = (n < HALF) ? o0 : o1;
#endif
    return bits < 0x80000000u;
}

// ---------------------------------------------------------------------------
// NN GEMM: C[M,N] = A[M,K] @ B[K,N] (+ bias). 64x64 tile, BK=16, 256 thr.
// LDS tiles stored k-major: inner loop = 2x ds_read_b128 + 16 v_fma_f32.
// ---------------------------------------------------------------------------
__global__ __launch_bounds__(256)
void gemm_nn(const float* __restrict__ A, const float* __restrict__ B,
             const float* __restrict__ bias, float* __restrict__ C,
             int M, int N, int K,
             long long sA, long long sB, long long sC) {
    __shared__ float As[16][68];   // [k][m]
    __shared__ float Bs[16][68];   // [k][n]
    const int tid = threadIdx.x;
    const int tx = tid & 15, ty = tid >> 4;
    const long long z = blockIdx.z;
    const float* Ab = A + z * sA;
    const float* Bb = B + z * sB;
    float*       Cb = C + z * sC;
    const int m0 = blockIdx.y * 64, n0 = blockIdx.x * 64;

    const int ar = tid >> 2;          // 0..63 (m within tile)
    const int ac = (tid & 3) * 4;     // 0,4,8,12 (k within tile)
    const int br = tid >> 4;          // 0..15 (k within tile)
    const int bc = (tid & 15) * 4;    // 0..60 (n within tile)

    float acc[4][4] = {};

    for (int k0 = 0; k0 < K; k0 += 16) {
        float4 av = *(const float4*)(Ab + (long long)(m0 + ar) * K + k0 + ac);
        float4 bv = *(const float4*)(Bb + (long long)(k0 + br) * N + n0 + bc);
        __syncthreads();
        As[ac + 0][ar] = av.x; As[ac + 1][ar] = av.y;
        As[ac + 2][ar] = av.z; As[ac + 3][ar] = av.w;
        *(float4*)&Bs[br][bc] = bv;
        __syncthreads();
#pragma unroll
        for (int kk = 0; kk < 16; ++kk) {
            float4 a = *(const float4*)&As[kk][ty * 4];
            float4 b = *(const float4*)&Bs[kk][tx * 4];
            float aa[4] = {a.x, a.y, a.z, a.w};
            float bb[4] = {b.x, b.y, b.z, b.w};
#pragma unroll
            for (int i = 0; i < 4; ++i)
#pragma unroll
                for (int j = 0; j < 4; ++j)
                    acc[i][j] = fmaf(aa[i], bb[j], acc[i][j]);
        }
    }

    float4 bvv = make_float4(0.f, 0.f, 0.f, 0.f);
    if (bias) bvv = *(const float4*)(bias + n0 + tx * 4);
#pragma unroll
    for (int i = 0; i < 4; ++i) {
        int m = m0 + ty * 4 + i;
        float4 o;
        o.x = acc[i][0] + bvv.x;
        o.y = acc[i][1] + bvv.y;
        o.z = acc[i][2] + bvv.z;
        o.w = acc[i][3] + bvv.w;
        *(float4*)(Cb + (long long)m * N + n0 + tx * 4) = o;
    }
}

// ---------------------------------------------------------------------------
// NT GEMM: C[M,N] = scale * A[M,K] @ B[N,K]^T  (S = 8 * Q K^T per batch)
// ---------------------------------------------------------------------------
__global__ __launch_bounds__(256)
void gemm_nt(const float* __restrict__ A, const float* __restrict__ B,
             float* __restrict__ C,
             int M, int N, int K, float scale,
             long long sA, long long sB, long long sC) {
    __shared__ float As[16][68];   // [k][m]
    __shared__ float Bs[16][68];   // [k][n]
    const int tid = threadIdx.x;
    const int tx = tid & 15, ty = tid >> 4;
    const long long z = blockIdx.z;
    const float* Ab = A + z * sA;
    const float* Bb = B + z * sB;
    float*       Cb = C + z * sC;
    const int m0 = blockIdx.y * 64, n0 = blockIdx.x * 64;

    const int ar = tid >> 2;          // 0..63
    const int ac = (tid & 3) * 4;     // 0,4,8,12

    float acc[4][4] = {};

    for (int k0 = 0; k0 < K; k0 += 16) {
        float4 av = *(const float4*)(Ab + (long long)(m0 + ar) * K + k0 + ac);
        float4 bv = *(const float4*)(Bb + (long long)(n0 + ar) * K + k0 + ac);
        __syncthreads();
        As[ac + 0][ar] = av.x; As[ac + 1][ar] = av.y;
        As[ac + 2][ar] = av.z; As[ac + 3][ar] = av.w;
        Bs[ac + 0][ar] = bv.x; Bs[ac + 1][ar] = bv.y;
        Bs[ac + 2][ar] = bv.z; Bs[ac + 3][ar] = bv.w;
        __syncthreads();
#pragma unroll
        for (int kk = 0; kk < 16; ++kk) {
            float4 a = *(const float4*)&As[kk][ty * 4];
            float4 b = *(const float4*)&Bs[kk][tx * 4];
            float aa[4] = {a.x, a.y, a.z, a.w};
            float bb[4] = {b.x, b.y, b.z, b.w};
#pragma unroll
            for (int i = 0; i < 4; ++i)
#pragma unroll
                for (int j = 0; j < 4; ++j)
                    acc[i][j] = fmaf(aa[i], bb[j], acc[i][j]);
        }
    }

#pragma unroll
    for (int i = 0; i < 4; ++i) {
        int m = m0 + ty * 4 + i;
        float4 o;
        o.x = acc[i][0] * scale;
        o.y = acc[i][1] * scale;
        o.z = acc[i][2] * scale;
        o.w = acc[i][3] * scale;
        *(float4*)(Cb + (long long)m * N + n0 + tx * 4) = o;
    }
}

// ---------------------------------------------------------------------------
// Row softmax + dropout (in place on S). One block (256 thr) per row of 2048.
// P[j] = keep(n) * 2 * exp(s[j]-m) / l
// ---------------------------------------------------------------------------
__global__ __launch_bounds__(256)
void softmax_dropout(float* __restrict__ S) {
    const int LK = LSEQ;
    const unsigned row = blockIdx.x;              // 0 .. 8191
    float* rowp = S + (long long)row * LK;
    __shared__ float buf[LSEQ];
    __shared__ float rbuf[256];
    const int tid = threadIdx.x;

    float m = -INFINITY;
    for (int j = tid; j < LK; j += 256) {
        float v = rowp[j];
        buf[j] = v;
        m = fmaxf(m, v);
    }
    rbuf[tid] = m;
    __syncthreads();
    for (int s = 128; s > 0; s >>= 1) {
        if (tid < s) rbuf[tid] = fmaxf(rbuf[tid], rbuf[tid + s]);
        __syncthreads();
    }
    m = rbuf[0];
    __syncthreads();

    float l = 0.f;
    for (int j = tid; j < LK; j += 256) {
        float e = expf(buf[j] - m);
        buf[j] = e;
        l += e;
    }
    rbuf[tid] = l;
    __syncthreads();
    for (int s = 128; s > 0; s >>= 1) {
        if (tid < s) rbuf[tid] += rbuf[tid + s];
        __syncthreads();
    }
    l = rbuf[0];

    const float inv = 2.0f / l;   // dropout /0.5 folded in
    for (int j = tid; j < LK; j += 256) {
        unsigned n = row * (unsigned)LK + (unsigned)j;
        rowp[j] = dropout_keep(n) ? buf[j] * inv : 0.0f;
    }
}

// ---------------------------------------------------------------------------
extern "C" void kernel_launch(void* const* d_in, const int* in_sizes, int n_in,
                              void* d_out, int out_size, void* d_ws, size_t ws_size,
                              hipStream_t stream) {
    const float* query = (const float*)d_in[0];
    const float* key_  = (const float*)d_in[1];
    const float* value = (const float*)d_in[2];
    const float* Wq = (const float*)d_in[3];
    const float* bq = (const float*)d_in[4];
    const float* Wk = (const float*)d_in[5];
    const float* bk = (const float*)d_in[6];
    const float* Wv = (const float*)d_in[7];
    const float* bv = (const float*)d_in[8];
    float* out = (float*)d_out;

    float* ws = (float*)d_ws;
    const long long QKV = (long long)MROWS * DMODEL;       // 8388608 floats
    float* Q = ws;
    float* K = ws + QKV;
    float* V = ws + 2 * QKV;
    float* S = ws + 3 * QKV;                               // 4*2048*2048 floats

    dim3 blk(256);

    // Projections: [8192,1024] = X @ W[1024,1024] + b
    dim3 g1(DMODEL / 64, MROWS / 64, 1);
    gemm_nn<<<g1, blk, 0, stream>>>(query, Wq, bq, Q, MROWS, DMODEL, DMODEL, 0, 0, 0);
    gemm_nn<<<g1, blk, 0, stream>>>(key_,  Wk, bk, K, MROWS, DMODEL, DMODEL, 0, 0, 0);
    gemm_nn<<<g1, blk, 0, stream>>>(value, Wv, bv, V, MROWS, DMODEL, DMODEL, 0, 0, 0);

    // S = 8 * Q K^T per batch: [2048,2048], K=1024
    dim3 g2(LSEQ / 64, LSEQ / 64, BATCH);
    gemm_nt<<<g2, blk, 0, stream>>>(Q, K, S, LSEQ, LSEQ, DMODEL, SCORE_SCALE,
                                    (long long)LSEQ * DMODEL,
                                    (long long)LSEQ * DMODEL,
                                    (long long)LSEQ * LSEQ);

    // softmax + dropout, in place on S (one block per row)
    softmax_dropout<<<dim3(BATCH * LSEQ), blk, 0, stream>>>(S);

    // O = P V per batch: [2048,1024], K=2048
    dim3 g3(DMODEL / 64, LSEQ / 64, BATCH);
    gemm_nn<<<g3, blk, 0, stream>>>(S, V, nullptr, out, LSEQ, DMODEL, LSEQ,
                                    (long long)LSEQ * LSEQ,
                                    (long long)LSEQ * DMODEL,
                                    (long long)LSEQ * DMODEL);
}

// Round 2
// 581.647 us; speedup vs baseline: 2.9639x; 2.9639x over previous
//
#include <hip/hip_runtime.h>
#include <math.h>

// Problem constants
#define BATCH  4
#define LSEQ   2048
#define DMODEL 1024
#define MROWS  (BATCH * LSEQ)   // 8192
#define SCORE_SCALE 8.0f        // sqrt(1024/16), reference MULTIPLIES

#define THREEFRY_PARTITIONABLE 1  // verified correct in round 1 (absmax 9.8e-4)

typedef __bf16 bf16_t;
typedef bf16_t bf16x8 __attribute__((ext_vector_type(8)));
typedef bf16_t bf16x4 __attribute__((ext_vector_type(4)));
typedef float  f32x4  __attribute__((ext_vector_type(4)));

#define LDSP(p) ((__attribute__((address_space(3))) void*)(p))
#define GLBP(p) ((const __attribute__((address_space(1))) void*)(p))

// ---------------------------------------------------------------------------
// threefry dropout (verified round 1)
// ---------------------------------------------------------------------------
__device__ __forceinline__ unsigned rotl32(unsigned x, int r) {
    return (x << r) | (x >> (32 - r));
}

__device__ __forceinline__ void threefry2x32(unsigned k0, unsigned k1,
                                             unsigned x0, unsigned x1,
                                             unsigned& o0, unsigned& o1) {
    const unsigned ks0 = k0, ks1 = k1, ks2 = k0 ^ k1 ^ 0x1BD11BDAu;
    x0 += ks0; x1 += ks1;
#define TF_R(r) { x0 += x1; x1 = rotl32(x1, r); x1 ^= x0; }
    TF_R(13) TF_R(15) TF_R(26) TF_R(6)
    x0 += ks1; x1 += ks2 + 1u;
    TF_R(17) TF_R(29) TF_R(16) TF_R(24)
    x0 += ks2; x1 += ks0 + 2u;
    TF_R(13) TF_R(15) TF_R(26) TF_R(6)
    x0 += ks0; x1 += ks1 + 3u;
    TF_R(17) TF_R(29) TF_R(16) TF_R(24)
    x0 += ks1; x1 += ks2 + 4u;
    TF_R(13) TF_R(15) TF_R(26) TF_R(6)
    x0 += ks2; x1 += ks0 + 5u;
#undef TF_R
    o0 = x0; o1 = x1;
}

__device__ __forceinline__ bool dropout_keep(unsigned n) {
    unsigned o0, o1;
#if THREEFRY_PARTITIONABLE
    threefry2x32(0u, 42u, 0u, n, o0, o1);
    unsigned bits = o0 ^ o1;
#else
    const unsigned HALF = (unsigned)(BATCH * LSEQ) * (unsigned)LSEQ / 2u;
    unsigned c0 = (n < HALF) ? n : (n - HALF);
    unsigned c1 = (n < HALF) ? (n + HALF) : n;
    threefry2x32(0u, 42u, c0, c1, o0, o1);
    unsigned bits = (n < HALF) ? o0 : o1;
#endif
    return bits < 0x80000000u;
}

// ---------------------------------------------------------------------------
// Split fp32 -> bf16 hi/lo (elementwise)
// ---------------------------------------------------------------------------
__global__ __launch_bounds__(256)
void split_f32(const float* __restrict__ X, bf16_t* __restrict__ hi,
               bf16_t* __restrict__ lo, int n) {
    int i = (blockIdx.x * 256 + threadIdx.x) * 4;
    if (i >= n) return;
    float4 v = *(const float4*)(X + i);
    bf16x4 h, l;
    h[0] = (bf16_t)v.x; l[0] = (bf16_t)(v.x - (float)h[0]);
    h[1] = (bf16_t)v.y; l[1] = (bf16_t)(v.y - (float)h[1]);
    h[2] = (bf16_t)v.z; l[2] = (bf16_t)(v.z - (float)h[2]);
    h[3] = (bf16_t)v.w; l[3] = (bf16_t)(v.w - (float)h[3]);
    *(bf16x4*)(hi + i) = h;
    *(bf16x4*)(lo + i) = l;
}

// W fp32 [K][N] -> W^T hi/lo bf16 [N][K]
__global__ __launch_bounds__(256)
void split_transpose(const float* __restrict__ W, bf16_t* __restrict__ Th,
                     bf16_t* __restrict__ Tl, int Kd, int Nd) {
    __shared__ float t[32][33];
    const int bx = blockIdx.x * 32;  // n
    const int by = blockIdx.y * 32;  // k
    const int tx = threadIdx.x & 31, ty = threadIdx.x >> 5;  // 32x8
#pragma unroll
    for (int i = 0; i < 4; ++i)
        t[ty + i * 8][tx] = W[(long long)(by + ty + i * 8) * Nd + bx + tx];
    __syncthreads();
#pragma unroll
    for (int i = 0; i < 4; ++i) {
        float v = t[tx][ty + i * 8];
        long long idx = (long long)(bx + ty + i * 8) * Kd + by + tx;
        bf16_t h = (bf16_t)v;
        Th[idx] = h;
        Tl[idx] = (bf16_t)(v - (float)h);
    }
}

// bf16 transpose per batch: src [rows][cols] -> dst [cols][rows]
__global__ __launch_bounds__(256)
void transpose_bf16(const bf16_t* __restrict__ src, bf16_t* __restrict__ dst,
                    int rows, int cols) {
    __shared__ bf16_t t[32][33];
    const long long z = blockIdx.z;
    src += z * (long long)rows * cols;
    dst += z * (long long)rows * cols;
    const int bx = blockIdx.x * 32;  // col
    const int by = blockIdx.y * 32;  // row
    const int tx = threadIdx.x & 31, ty = threadIdx.x >> 5;
#pragma unroll
    for (int i = 0; i < 4; ++i)
        t[ty + i * 8][tx] = src[(long long)(by + ty + i * 8) * cols + bx + tx];
    __syncthreads();
#pragma unroll
    for (int i = 0; i < 4; ++i)
        dst[(long long)(bx + ty + i * 8) * rows + by + tx] = t[tx][ty + i * 8];
}

// ---------------------------------------------------------------------------
// MFMA GEMM: C[M,N] = scale * (Ah+Al)[M,K] @ (Bh+Bl)[N,K]^T (+bias)
// Both operands k-contiguous (B given pre-transposed). 128x128 tile, BK=32,
// 256 threads = 4 waves, each wave 64x64 via 4x4 subtiles of 16x16x32 MFMA.
// global_load_lds width 16 staging (m97 structure).
// SPLIT: 3 MFMAs per product (hi*hi + hi*lo + lo*hi).
// OUT: 0 = fp32*scale, 1 = bf16 hi/lo pair (+bias), 2 = bf16 (+bias)
// ---------------------------------------------------------------------------
template <int SPLIT, int OUT>
__global__ __launch_bounds__(256)
void gemm_mfma(const bf16_t* __restrict__ Ah, const bf16_t* __restrict__ Al,
               const bf16_t* __restrict__ Bh, const bf16_t* __restrict__ Bl,
               const float* __restrict__ bias,
               float* __restrict__ Cf, bf16_t* __restrict__ Ch,
               bf16_t* __restrict__ Cl,
               int M, int N, int K, float scale,
               long long sA, long long sB, long long sC) {
    __shared__ __align__(16) bf16_t smem[(SPLIT ? 4 : 2) * 128 * 32];
    bf16_t* sAh = smem;
    bf16_t* sBh = smem + 128 * 32;
    bf16_t* sAl = SPLIT ? smem + 2 * 128 * 32 : nullptr;
    bf16_t* sBl = SPLIT ? smem + 3 * 128 * 32 : nullptr;

    const int tid = threadIdx.x;
    const int lane = tid & 63;
    const int wave = tid >> 6;
    const int quad = lane >> 4;   // 0..3
    const int l16 = lane & 15;
    const int wm = (wave & 1) * 64;
    const int wn = (wave >> 1) * 64;
    const long long z = blockIdx.z;
    const int m0 = blockIdx.y * 128, n0 = blockIdx.x * 128;

    const bf16_t* gAh = Ah + z * sA;
    const bf16_t* gBh = Bh + z * sB;
    const bf16_t* gAl = SPLIT ? Al + z * sA : nullptr;
    const bf16_t* gBl = SPLIT ? Bl + z * sB : nullptr;

    // staging: wave stages rows [wave*32, wave*32+32) of each tile, 2x16 rows
    const int srow = wave * 32;
    const int lrow = lane >> 2;        // 0..15
    const int lcol = (lane & 3) * 8;   // 0,8,16,24

    f32x4 acc[4][4];
#pragma unroll
    for (int i = 0; i < 4; ++i)
#pragma unroll
        for (int j = 0; j < 4; ++j)
            acc[i][j] = (f32x4){0.f, 0.f, 0.f, 0.f};

    for (int k0 = 0; k0 < K; k0 += 32) {
        __syncthreads();  // previous-iter LDS reads done
#pragma unroll
        for (int c = 0; c < 2; ++c) {
            const int r = srow + c * 16;
            const long long arow = (long long)(m0 + r + lrow) * K + k0 + lcol;
            const long long brow = (long long)(n0 + r + lrow) * K + k0 + lcol;
            __builtin_amdgcn_global_load_lds(GLBP(gAh + arow), LDSP(sAh + r * 32), 16, 0, 0);
            __builtin_amdgcn_global_load_lds(GLBP(gBh + brow), LDSP(sBh + r * 32), 16, 0, 0);
            if constexpr (SPLIT) {
                __builtin_amdgcn_global_load_lds(GLBP(gAl + arow), LDSP(sAl + r * 32), 16, 0, 0);
                __builtin_amdgcn_global_load_lds(GLBP(gBl + brow), LDSP(sBl + r * 32), 16, 0, 0);
            }
        }
        __syncthreads();  // drains vmcnt (global_load_lds) before reads

        bf16x8 afh[4], bfh[4];
        bf16x8 afl[4], bfl[4];
#pragma unroll
        for (int i = 0; i < 4; ++i) {
            const int ao = (wm + i * 16 + l16) * 32 + quad * 8;
            const int bo = (wn + i * 16 + l16) * 32 + quad * 8;
            afh[i] = *(const bf16x8*)(sAh + ao);
            bfh[i] = *(const bf16x8*)(sBh + bo);
            if constexpr (SPLIT) {
                afl[i] = *(const bf16x8*)(sAl + ao);
                bfl[i] = *(const bf16x8*)(sBl + bo);
            }
        }
#pragma unroll
        for (int i = 0; i < 4; ++i)
#pragma unroll
            for (int j = 0; j < 4; ++j) {
                acc[i][j] = __builtin_amdgcn_mfma_f32_16x16x32_bf16(afh[i], bfh[j], acc[i][j], 0, 0, 0);
                if constexpr (SPLIT) {
                    acc[i][j] = __builtin_amdgcn_mfma_f32_16x16x32_bf16(afh[i], bfl[j], acc[i][j], 0, 0, 0);
                    acc[i][j] = __builtin_amdgcn_mfma_f32_16x16x32_bf16(afl[i], bfh[j], acc[i][j], 0, 0, 0);
                }
            }
    }

    // epilogue: D[row=(quad*4+r)][col=l16] per 16x16 subtile
#pragma unroll
    for (int i = 0; i < 4; ++i)
#pragma unroll
        for (int j = 0; j < 4; ++j) {
            const int n = n0 + wn + j * 16 + l16;
            float bv = 0.f;
            if constexpr (OUT != 0) bv = bias[n];
#pragma unroll
            for (int r = 0; r < 4; ++r) {
                const int m = m0 + wm + i * 16 + quad * 4 + r;
                float v = acc[i][j][r];
                if constexpr (OUT == 0) {
                    Cf[z * sC + (long long)m * N + n] = v * scale;
                } else if constexpr (OUT == 1) {
                    v += bv;
                    bf16_t h = (bf16_t)v;
                    const long long idx = (long long)m * N + n;
                    Ch[idx] = h;
                    Cl[idx] = (bf16_t)(v - (float)h);
                } else {
                    v += bv;
                    Ch[(long long)m * N + n] = (bf16_t)v;
                }
            }
        }
}

// ---------------------------------------------------------------------------
// Row softmax + dropout: S fp32 (read-only) -> P bf16.
// ---------------------------------------------------------------------------
__global__ __launch_bounds__(256)
void softmax_dropout(const float* __restrict__ S, bf16_t* __restrict__ P) {
    const int LK = LSEQ;
    const unsigned row = blockIdx.x;
    const float* rowp = S + (long long)row * LK;
    bf16_t* prow = P + (long long)row * LK;
    __shared__ float buf[LSEQ];
    __shared__ float rbuf[256];
    const int tid = threadIdx.x;

    float m = -INFINITY;
    for (int j = tid; j < LK; j += 256) {
        float v = rowp[j];
        buf[j] = v;
        m = fmaxf(m, v);
    }
    rbuf[tid] = m;
    __syncthreads();
    for (int s = 128; s > 0; s >>= 1) {
        if (tid < s) rbuf[tid] = fmaxf(rbuf[tid], rbuf[tid + s]);
        __syncthreads();
    }
    m = rbuf[0];
    __syncthreads();

    float l = 0.f;
    for (int j = tid; j < LK; j += 256) {
        float e = expf(buf[j] - m);
        buf[j] = e;
        l += e;
    }
    rbuf[tid] = l;
    __syncthreads();
    for (int s = 128; s > 0; s >>= 1) {
        if (tid < s) rbuf[tid] += rbuf[tid + s];
        __syncthreads();
    }
    l = rbuf[0];

    const float inv = 2.0f / l;  // dropout /0.5 folded in
    for (int j = tid; j < LK; j += 256) {
        unsigned n = row * (unsigned)LK + (unsigned)j;
        float p = dropout_keep(n) ? buf[j] * inv : 0.0f;
        prow[j] = (bf16_t)p;
    }
}

// ---------------------------------------------------------------------------
extern "C" void kernel_launch(void* const* d_in, const int* in_sizes, int n_in,
                              void* d_out, int out_size, void* d_ws, size_t ws_size,
                              hipStream_t stream) {
    const float* query = (const float*)d_in[0];
    const float* key_  = (const float*)d_in[1];
    const float* value = (const float*)d_in[2];
    const float* Wq = (const float*)d_in[3];
    const float* bq = (const float*)d_in[4];
    const float* Wk = (const float*)d_in[5];
    const float* bk = (const float*)d_in[6];
    const float* Wv = (const float*)d_in[7];
    const float* bv = (const float*)d_in[8];
    float* out = (float*)d_out;

    // ws layout (bytes), QKVB = 8192*1024*2 = 16.8MB; total 9*QKVB = 151MB
    char* w = (char*)d_ws;
    const size_t QKVB = (size_t)MROWS * DMODEL * 2;
    bf16_t* Qhi = (bf16_t*)(w);
    bf16_t* Qlo = (bf16_t*)(w + QKVB);
    bf16_t* Khi = (bf16_t*)(w + 2 * QKVB);
    bf16_t* Klo = (bf16_t*)(w + 3 * QKVB);
    bf16_t* VT  = (bf16_t*)(w + 4 * QKVB);
    float*  S   = (float*)(w + 5 * QKVB);             // 4*QKVB bytes
    // phase-A scratch aliased inside S region:
    bf16_t* Xhi = (bf16_t*)(w + 5 * QKVB);
    bf16_t* Xlo = (bf16_t*)(w + 6 * QKVB);
    bf16_t* Vb  = (bf16_t*)(w + 7 * QKVB);
    bf16_t* WTh = (bf16_t*)(w + 8 * QKVB);
    bf16_t* WTl = (bf16_t*)(w + 8 * QKVB + (size_t)DMODEL * DMODEL * 2);
    bf16_t* P   = Qhi;  // aliases Q region (free after QK^T)

    dim3 b256(256);
    const int NELEM = MROWS * DMODEL;
    dim3 gsplit(NELEM / (256 * 4));
    dim3 gwt(DMODEL / 32, DMODEL / 32);
    dim3 gproj(DMODEL / 128, MROWS / 128, 1);

    // --- V path (first, so Vb scratch dies before S is written)
    split_transpose<<<gwt, b256, 0, stream>>>(Wv, WTh, WTl, DMODEL, DMODEL);
    split_f32<<<gsplit, b256, 0, stream>>>(value, Xhi, Xlo, NELEM);
    gemm_mfma<1, 2><<<gproj, b256, 0, stream>>>(Xhi, Xlo, WTh, WTl, bv,
                                                nullptr, Vb, nullptr,
                                                MROWS, DMODEL, DMODEL, 1.f, 0, 0, 0);
    transpose_bf16<<<dim3(DMODEL / 32, LSEQ / 32, BATCH), b256, 0, stream>>>(
        Vb, VT, LSEQ, DMODEL);

    // --- Q
    split_transpose<<<gwt, b256, 0, stream>>>(Wq, WTh, WTl, DMODEL, DMODEL);
    split_f32<<<gsplit, b256, 0, stream>>>(query, Xhi, Xlo, NELEM);
    gemm_mfma<1, 1><<<gproj, b256, 0, stream>>>(Xhi, Xlo, WTh, WTl, bq,
                                                nullptr, Qhi, Qlo,
                                                MROWS, DMODEL, DMODEL, 1.f, 0, 0, 0);
    // --- K
    split_transpose<<<gwt, b256, 0, stream>>>(Wk, WTh, WTl, DMODEL, DMODEL);
    split_f32<<<gsplit, b256, 0, stream>>>(key_, Xhi, Xlo, NELEM);
    gemm_mfma<1, 1><<<gproj, b256, 0, stream>>>(Xhi, Xlo, WTh, WTl, bk,
                                                nullptr, Khi, Klo,
                                                MROWS, DMODEL, DMODEL, 1.f, 0, 0, 0);

    // --- S = 8 * Q K^T (batched)
    gemm_mfma<1, 0><<<dim3(LSEQ / 128, LSEQ / 128, BATCH), b256, 0, stream>>>(
        Qhi, Qlo, Khi, Klo, nullptr, S, nullptr, nullptr,
        LSEQ, LSEQ, DMODEL, SCORE_SCALE,
        (long long)LSEQ * DMODEL, (long long)LSEQ * DMODEL,
        (long long)LSEQ * LSEQ);

    // --- softmax + dropout -> P bf16 (aliases Q region)
    softmax_dropout<<<dim3(MROWS), b256, 0, stream>>>(S, P);

    // --- O = P V (plain bf16), B operand = V^T [D][LK] per batch
    gemm_mfma<0, 0><<<dim3(DMODEL / 128, LSEQ / 128, BATCH), b256, 0, stream>>>(
        P, nullptr, VT, nullptr, nullptr, out, nullptr, nullptr,
        LSEQ, DMODEL, LSEQ, 1.f,
        (long long)LSEQ * LSEQ, (long long)DMODEL * LSEQ,
        (long long)LSEQ * DMODEL);
}